// Round 12
// baseline (7416.837 us; speedup 1.0000x reference)
//
#include <hip/hip_runtime.h>
#include <stdint.h>
#include <math.h>

#define BB 4096
#define HH 512
#define VV 32000
#define NT 15
#define STF 2097152   // BB*HH floats
#define NXT 250       // VV/128

struct KeysArg { uint32_t w[2*NT]; };

// JAX Threefry-2x32 (20 rounds, standard rotation/key schedule)
__host__ __device__ inline void tf2x32(uint32_t k0, uint32_t k1,
                                       uint32_t x0, uint32_t x1,
                                       uint32_t& o0, uint32_t& o1) {
  uint32_t ks2 = k0 ^ k1 ^ 0x1BD11BDAu;
  x0 += k0; x1 += k1;
#define TF_R(r) { x0 += x1; x1 = (x1 << (r)) | (x1 >> (32 - (r))); x1 ^= x0; }
  TF_R(13) TF_R(15) TF_R(26) TF_R(6)
  x0 += k1; x1 += ks2 + 1u;
  TF_R(17) TF_R(29) TF_R(16) TF_R(24)
  x0 += ks2; x1 += k0 + 2u;
  TF_R(13) TF_R(15) TF_R(26) TF_R(6)
  x0 += k0; x1 += k1 + 3u;
  TF_R(17) TF_R(29) TF_R(16) TF_R(24)
  x0 += k1; x1 += ks2 + 4u;
  TF_R(13) TF_R(15) TF_R(26) TF_R(6)
  x0 += ks2; x1 += k0 + 5u;
#undef TF_R
  o0 = x0; o1 = x1;
}

// direct global->LDS DMA, 16B per lane at wave-uniform LDS base + lane*16
__device__ inline void gll16(const float* g, float* l) {
  __builtin_amdgcn_global_load_lds(
      (const __attribute__((address_space(1))) void*)g,
      (__attribute__((address_space(3))) void*)l, 16, 0, 0);
}

// ---- A-tile XOR swizzle (bank-conflict fix) ----
// A LDS layout is [row][16k] linear; reads a4[mm] pull one 16B chunk per row
// with 4 ty-rows 512B apart -> same bank (4-way conflict). Fix: store global
// chunk (c ^ s(row)) at LDS chunk c, where s(row) = (row>>3)&3 (= ty&3 for
// readers). gll writes linearly, so the XOR goes on the per-lane GLOBAL
// source; readers index chunk kk4 ^ (ty&3) -> 4 distinct bank groups.

// 128x128x16-tile f32 GEMM, 256 threads, 8x8/thread.
// global_load_lds staging, double-buffered LDS, one barrier per K-step.
// No min-waves launch_bounds (R6: spill disaster).
__global__ __launch_bounds__(256)
void gemm_sk(const float* __restrict__ A0, int lda0,
             const float* __restrict__ W0, int koff0, int Klen0,
             const float* __restrict__ A1, int lda1,
             const float* __restrict__ W1, int koff1, int Klen1,
             int ldw,
             const float* __restrict__ bias,
             float* __restrict__ C0, float* __restrict__ C1, int ldc)
{
  const float* A; const float* W; float* C; int lda, koff, Klen;
  if (blockIdx.z == 0) { A = A0; lda = lda0; W = W0; koff = koff0; Klen = Klen0; C = C0; }
  else                 { A = A1; lda = lda1; W = W1; koff = koff1; Klen = Klen1; C = C1; }

  __shared__ float As[2][128 * 16];   // [row][k-chunk swizzled]
  __shared__ float Ws[2][16 * 128];   // [k][n] row-major
  const int tid = threadIdx.x;
  const int lane = tid & 63, wv = tid >> 6;
  const int m0 = blockIdx.y * 128;
  const int n0 = blockIdx.x * 128;
  const int tx = tid & 15, ty = tid >> 4;

  float acc[8][8];
  #pragma unroll
  for (int i = 0; i < 8; ++i)
    #pragma unroll
    for (int j = 0; j < 8; ++j) acc[i][j] = 0.0f;

  const int a_row_in = (lane >> 2);
  const int w_row_in = (lane >> 5);
  const int w_col    = (lane & 31) * 4;
  const int tys      = ty & 3;        // reader swizzle key

  auto STAGE = [&](int buf, int kt) {
    const int k0 = koff + (kt << 4);
    #pragma unroll
    for (int i = 0; i < 2; ++i) {
      const int seg = wv * 2 + i;
      const int s = (seg * 2 + (lane >> 5)) & 3;          // s(row)
      const int a_chunk = ((lane & 3) ^ s) * 4;           // swizzled source
      gll16(A + (size_t)(m0 + seg * 16 + a_row_in) * lda + (k0 + a_chunk),
            &As[buf][seg * 256]);
      gll16(W + (size_t)(k0 + seg * 2 + w_row_in) * ldw + (n0 + w_col),
            &Ws[buf][seg * 256]);
    }
  };

  const int nkt = Klen >> 4;
  STAGE(0, 0);
  asm volatile("s_waitcnt vmcnt(0)" ::: "memory");
  __syncthreads();

  int cur = 0;
  for (int kt = 0; kt < nkt; ++kt) {
    if (kt + 1 < nkt) STAGE(cur ^ 1, kt + 1);
    #pragma unroll
    for (int kk4 = 0; kk4 < 4; ++kk4) {
      const int cs = (kk4 ^ tys) * 4;                     // unswizzle on read
      float4 a4[8];
      #pragma unroll
      for (int mm = 0; mm < 8; ++mm)
        a4[mm] = *(const float4*)&As[cur][(ty * 8 + mm) * 16 + cs];
      #pragma unroll
      for (int q = 0; q < 4; ++q) {
        const int kk = kk4 * 4 + q;
        float4 b0 = *(const float4*)&Ws[cur][kk * 128 + tx * 4];
        float4 b1 = *(const float4*)&Ws[cur][kk * 128 + tx * 4 + 64];
        float br[8] = {b0.x,b0.y,b0.z,b0.w,b1.x,b1.y,b1.z,b1.w};
        #pragma unroll
        for (int mm = 0; mm < 8; ++mm) {
          float av = (q == 0) ? a4[mm].x : (q == 1) ? a4[mm].y
                   : (q == 2) ? a4[mm].z : a4[mm].w;
          #pragma unroll
          for (int j = 0; j < 8; ++j)
            acc[mm][j] = fmaf(av, br[j], acc[mm][j]);
        }
      }
    }
    asm volatile("s_waitcnt vmcnt(0)" ::: "memory");
    __syncthreads();
    cur ^= 1;
  }

  const int wn = tx * 4;
  #pragma unroll
  for (int i = 0; i < 8; ++i) {
    const int m = m0 + ty * 8 + i;
    float* dst = C + (size_t)m * ldc + (n0 + wn);
    float4 o0, o1;
    o0.x = acc[i][0]; o0.y = acc[i][1]; o0.z = acc[i][2]; o0.w = acc[i][3];
    o1.x = acc[i][4]; o1.y = acc[i][5]; o1.z = acc[i][6]; o1.w = acc[i][7];
    if (bias) {
      o0.x += bias[n0+wn+0]; o0.y += bias[n0+wn+1];
      o0.z += bias[n0+wn+2]; o0.w += bias[n0+wn+3];
      o1.x += bias[n0+wn+64]; o1.y += bias[n0+wn+65];
      o1.z += bias[n0+wn+66]; o1.w += bias[n0+wn+67];
    }
    *(float4*)dst        = o0;
    *(float4*)(dst + 64) = o1;
  }
}

// LSTM gate update: z = z0 + z1 + bias
__global__ __launch_bounds__(256)
void gate_kernel(const float* __restrict__ z0, const float* __restrict__ z1,
                 const float* __restrict__ bias,
                 const float* __restrict__ cin,
                 float* __restrict__ hout, float* __restrict__ cout,
                 float* __restrict__ sh, float* __restrict__ sc)
{
  int idx = blockIdx.x * 256 + threadIdx.x;
  int b = idx >> 9, j = idx & 511;
  const size_t r2 = (size_t)b * 2048;
  float zi = z0[r2+j]      + z1[r2+j]      + bias[j];
  float zf = z0[r2+j+512]  + z1[r2+j+512]  + bias[j+512];
  float zg = z0[r2+j+1024] + z1[r2+j+1024] + bias[j+1024];
  float zo = z0[r2+j+1536] + z1[r2+j+1536] + bias[j+1536];
  float si = 1.0f/(1.0f+expf(-zi));
  float sf = 1.0f/(1.0f+expf(-zf));
  float so = 1.0f/(1.0f+expf(-zo));
  float c = sf * cin[idx] + si * tanhf(zg);
  float h = so * tanhf(c);
  cout[idx] = c; hout[idx] = h;
  if (sh) { sh[idx] = h; sc[idx] = c; }
}

// Fused decode-pipeline kernel: blocks [0,SB) run row-stats (bit-identical
// to the old rowstat_kernel reduction) + the R7-proven sampler for chunk c;
// blocks [SB, SB+GB) run the gll GEMM computing chunk c+1's logits.
// SB=0 -> pure GEMM launch; GB=0 -> pure sampler launch.
__global__ __launch_bounds__(256)
void fused_sg(const float* __restrict__ logitsS,
              float* __restrict__ out, KeysArg keys, int bbaseS, int SB,
              const float* __restrict__ AG, const float* __restrict__ Wd,
              const float* __restrict__ bd, float* __restrict__ logitsG)
{
  __shared__ float As[2][128 * 16];
  __shared__ float Ws[2][16 * 128];
  __shared__ float rv[NT][4];
  __shared__ uint32_t ri[NT][4];
  __shared__ float sm[4], ssum[4], swsum[4], sbc[2];

  const int tid = threadIdx.x;

  if ((int)blockIdx.x < SB) {
    // ---------------- sampler path (stats + R7 body) ----------------
    const int l = blockIdx.x;
    const int b = bbaseS + l;
    const float* x = logitsS + (size_t)l * VV;

    // row stats — bit-identical to old rowstat_kernel
    float m = -INFINITY;
    for (int v = tid; v < VV; v += 256) m = fmaxf(m, x[v]);
    #pragma unroll
    for (int off = 32; off; off >>= 1) m = fmaxf(m, __shfl_down(m, off));
    if ((tid & 63) == 0) sm[tid >> 6] = m;
    __syncthreads();
    m = fmaxf(fmaxf(sm[0], sm[1]), fmaxf(sm[2], sm[3]));
    float s = 0.0f, w = 0.0f;
    for (int v = tid; v < VV; v += 256) {
      float d = x[v] - m;
      float e = expf(d);
      s += e; w += d * e;
    }
    #pragma unroll
    for (int off = 32; off; off >>= 1) { s += __shfl_down(s, off); w += __shfl_down(w, off); }
    if ((tid & 63) == 0) { ssum[tid >> 6] = s; swsum[tid >> 6] = w; }
    __syncthreads();
    if (tid == 0) {
      s = ssum[0]+ssum[1]+ssum[2]+ssum[3];
      w = swsum[0]+swsum[1]+swsum[2]+swsum[3];
      float ls0 = logf(s);
      sbc[0] = ls0; sbc[1] = ls0 - w / s;   // ls, ent
    }
    __syncthreads();
    const float ls = sbc[0], ent = sbc[1];

    float bv[NT];
    uint32_t bi[NT];
    float thr[NT];
    #pragma unroll
    for (int t = 0; t < NT; ++t) { bv[t] = -INFINITY; bi[t] = 0; thr[t] = 1.0f; }

    const uint32_t pbase = (uint32_t)b * (uint32_t)VV;
    for (int v = tid; v < VV; v += 256) {
      const float lp = (x[v] - m) - ls;   // JAX order: (x - max) - logsum
      const uint32_t p = pbase + (uint32_t)v;
      #pragma unroll
      for (int t = 0; t < NT; ++t) {
        uint32_t o0, o1;
        tf2x32(keys.w[2*t], keys.w[2*t+1], 0u, p, o0, o1);
        const uint32_t bits = o0 ^ o1;
        const float uf = __uint_as_float((bits >> 9) | 0x3f800000u);
        if (__any(uf >= thr[t])) {
          float u = fmaxf(uf - 1.0f, 1.17549435e-38f);
          float g = -logf(-logf(u)) + lp;
          bool improved = (uf >= thr[t]) && (g > bv[t]);
          if (improved) { bv[t] = g; bi[t] = (uint32_t)v; }
          if (__any(improved)) {
            float wb = bv[t];
            #pragma unroll
            for (int off = 1; off < 64; off <<= 1)
              wb = fmaxf(wb, __shfl_xor(wb, off));
            float us = expf(-expf(-(wb + ls)));
            thr[t] = 1.0f + us * 0.999999f;   // conservative: never false-skip
          }
        }
      }
    }

    const int lane = tid & 63, wq = tid >> 6;
    #pragma unroll
    for (int t = 0; t < NT; ++t) {
      float v = bv[t]; uint32_t idx = bi[t];
      #pragma unroll
      for (int off = 32; off; off >>= 1) {
        float ov = __shfl_down(v, off);
        uint32_t oi = __shfl_down(idx, off);
        if (ov > v || (ov == v && oi < idx)) { v = ov; idx = oi; }
      }
      if (lane == 0) { rv[t][wq] = v; ri[t][wq] = idx; }
    }
    __syncthreads();
    if (tid < NT) {
      const int t = tid;
      float v = rv[t][0]; uint32_t idx = ri[t][0];
      #pragma unroll
      for (int q = 1; q < 4; ++q) {
        float ov = rv[t][q]; uint32_t oi = ri[t][q];
        if (ov > v || (ov == v && oi < idx)) { v = ov; idx = oi; }
      }
      out[(size_t)b * 30 + t]      = (float)idx;              // message
      out[(size_t)b * 30 + 15 + t] = 0.0f;                    // zero tail
      out[122880 + (size_t)t * BB + b] = (x[idx] - m) - ls;   // lp
      out[184320 + (size_t)t * BB + b] = ent;                 // ent
    }
    return;
  }

  // ---------------- GEMM path (K=512, ldw=ldc=VV) ----------------
  const int gb = (int)blockIdx.x - SB;
  const int m0 = (gb / NXT) * 128;
  const int n0 = (gb % NXT) * 128;
  const int lane = tid & 63, wv = tid >> 6;
  const int tx = tid & 15, ty = tid >> 4;

  float acc[8][8];
  #pragma unroll
  for (int i = 0; i < 8; ++i)
    #pragma unroll
    for (int j = 0; j < 8; ++j) acc[i][j] = 0.0f;

  const int a_row_in = (lane >> 2);
  const int w_row_in = (lane >> 5);
  const int w_col    = (lane & 31) * 4;
  const int tys      = ty & 3;

  auto STAGE = [&](int buf, int kt) {
    const int k0 = kt << 4;
    #pragma unroll
    for (int i = 0; i < 2; ++i) {
      const int seg = wv * 2 + i;
      const int s = (seg * 2 + (lane >> 5)) & 3;
      const int a_chunk = ((lane & 3) ^ s) * 4;
      gll16(AG + (size_t)(m0 + seg * 16 + a_row_in) * 512 + (k0 + a_chunk),
            &As[buf][seg * 256]);
      gll16(Wd + (size_t)(k0 + seg * 2 + w_row_in) * VV + (n0 + w_col),
            &Ws[buf][seg * 256]);
    }
  };

  STAGE(0, 0);
  asm volatile("s_waitcnt vmcnt(0)" ::: "memory");
  __syncthreads();

  int cur = 0;
  for (int kt = 0; kt < 32; ++kt) {
    if (kt + 1 < 32) STAGE(cur ^ 1, kt + 1);
    #pragma unroll
    for (int kk4 = 0; kk4 < 4; ++kk4) {
      const int cs = (kk4 ^ tys) * 4;
      float4 a4[8];
      #pragma unroll
      for (int mm = 0; mm < 8; ++mm)
        a4[mm] = *(const float4*)&As[cur][(ty * 8 + mm) * 16 + cs];
      #pragma unroll
      for (int q = 0; q < 4; ++q) {
        const int kk = kk4 * 4 + q;
        float4 b0 = *(const float4*)&Ws[cur][kk * 128 + tx * 4];
        float4 b1 = *(const float4*)&Ws[cur][kk * 128 + tx * 4 + 64];
        float br[8] = {b0.x,b0.y,b0.z,b0.w,b1.x,b1.y,b1.z,b1.w};
        #pragma unroll
        for (int mm = 0; mm < 8; ++mm) {
          float av = (q == 0) ? a4[mm].x : (q == 1) ? a4[mm].y
                   : (q == 2) ? a4[mm].z : a4[mm].w;
          #pragma unroll
          for (int j = 0; j < 8; ++j)
            acc[mm][j] = fmaf(av, br[j], acc[mm][j]);
        }
      }
    }
    asm volatile("s_waitcnt vmcnt(0)" ::: "memory");
    __syncthreads();
    cur ^= 1;
  }

  const int wn = tx * 4;
  #pragma unroll
  for (int i = 0; i < 8; ++i) {
    float* dst = logitsG + (size_t)(m0 + ty * 8 + i) * VV + (n0 + wn);
    float4 o0, o1;
    o0.x = acc[i][0] + bd[n0+wn+0];  o0.y = acc[i][1] + bd[n0+wn+1];
    o0.z = acc[i][2] + bd[n0+wn+2];  o0.w = acc[i][3] + bd[n0+wn+3];
    o1.x = acc[i][4] + bd[n0+wn+64]; o1.y = acc[i][5] + bd[n0+wn+65];
    o1.z = acc[i][6] + bd[n0+wn+66]; o1.w = acc[i][7] + bd[n0+wn+67];
    *(float4*)dst        = o0;
    *(float4*)(dst + 64) = o1;
  }
}

extern "C" void kernel_launch(void* const* d_in, const int* in_sizes, int n_in,
                              void* d_out, int out_size, void* d_ws, size_t ws_size,
                              hipStream_t stream)
{
  const float* inp = (const float*)d_in[0];
  const float* Wx0 = (const float*)d_in[1];
  const float* Wh0 = (const float*)d_in[2];
  const float* b0v = (const float*)d_in[3];
  const float* Wx1 = (const float*)d_in[4];
  const float* Wh1 = (const float*)d_in[5];
  const float* b1v = (const float*)d_in[6];
  const float* Wd  = (const float*)d_in[7];
  const float* bdv = (const float*)d_in[8];
  float* out = (float*)d_out;
  float* ws = (float*)d_ws;

  // ws layout (floats): h0,c0,h1,c1 | pad | region.
  // LSTM phase: region = z0,z1. Decode: region = logits ping-pong.
  float* h0 = ws;
  float* c0 = ws + (size_t)STF;
  float* h1 = ws + (size_t)2*STF;
  float* c1 = ws + (size_t)3*STF;
  float* region = ws + (size_t)4*STF + 12288;
  float* z0 = region;
  float* z1 = region + (size_t)4096*2048;

  size_t ws_floats = ws_size / 4;
  size_t base = (size_t)4*STF + 12288;
  int CH = 512;   // decoder rows per chunk (ping-pong: need 2 buffers)
  while (CH > 128 && base + (size_t)2*CH*VV > ws_floats) CH >>= 1;
  float* logitsA = region;
  float* logitsB = region + (size_t)CH*VV;

  hipMemsetAsync(ws, 0, (size_t)4*STF*sizeof(float), stream);  // zero states

  for (int t = 0; t < 4; ++t) {
    gemm_sk<<<dim3(2048/128, 4096/128, 2), 256, 0, stream>>>(
        h0, 512, Wh0, 0, 512,
        inp + t*256, 1024, Wx0, 0, 256,
        2048, nullptr, z0, z1, 2048);
    gate_kernel<<<STF/256, 256, 0, stream>>>(
        z0, z1, b0v, c0, h0, c0,
        (t==3) ? out + 245760 : (float*)nullptr,
        (t==3) ? out + 245760 + STF : (float*)nullptr);
    gemm_sk<<<dim3(2048/128, 4096/128, 2), 256, 0, stream>>>(
        h0, 512, Wx1, 0, 512,
        h1, 512, Wh1, 0, 512,
        2048, nullptr, z0, z1, 2048);
    gate_kernel<<<STF/256, 256, 0, stream>>>(
        z0, z1, b1v, c1, h1, c1, (float*)nullptr, (float*)nullptr);
  }

  // host-side partitionable (fold-like) split of key(42):
  // key_t = (o0, o1) = threefry((0,42), x0=0, x1=t)
  KeysArg ka;
  for (int t = 0; t < NT; ++t) {
    uint32_t o0, o1;
    tf2x32(0u, 42u, 0u, (uint32_t)t, o0, o1);
    ka.w[2*t] = o0; ka.w[2*t+1] = o1;
  }

  const int nch = 4096 / CH;
  const int GB = NXT * (CH / 128);   // gemm blocks per chunk

  // pipeline: gemm(0); { F(stats+sample c || gemm c+1) } ...
  fused_sg<<<GB, 256, 0, stream>>>(
      nullptr, out, ka, 0, 0, h1, Wd, bdv, logitsA);

  for (int c = 0; c < nch; ++c) {
    float* lgS = (c & 1) ? logitsB : logitsA;
    float* lgG = (c & 1) ? logitsA : logitsB;
    const bool more = (c + 1 < nch);
    fused_sg<<<CH + (more ? GB : 0), 256, 0, stream>>>(
        lgS, out, ka, c * CH, CH,
        more ? (h1 + (size_t)(c + 1) * CH * 512) : h1, Wd, bdv, lgG);
  }
}

// Round 13
// 7311.346 us; speedup vs baseline: 1.0144x; 1.0144x over previous
//
#include <hip/hip_runtime.h>
#include <stdint.h>
#include <math.h>

#define BB 4096
#define HH 512
#define VV 32000
#define NT 15
#define STF 2097152   // BB*HH floats
#define NXT 250       // VV/128
#define VSPLIT 16128  // half-row split point: 63*256; tail 15872 = 62*256

struct KeysArg { uint32_t w[2*NT]; };

// JAX Threefry-2x32 (20 rounds, standard rotation/key schedule)
__host__ __device__ inline void tf2x32(uint32_t k0, uint32_t k1,
                                       uint32_t x0, uint32_t x1,
                                       uint32_t& o0, uint32_t& o1) {
  uint32_t ks2 = k0 ^ k1 ^ 0x1BD11BDAu;
  x0 += k0; x1 += k1;
#define TF_R(r) { x0 += x1; x1 = (x1 << (r)) | (x1 >> (32 - (r))); x1 ^= x0; }
  TF_R(13) TF_R(15) TF_R(26) TF_R(6)
  x0 += k1; x1 += ks2 + 1u;
  TF_R(17) TF_R(29) TF_R(16) TF_R(24)
  x0 += ks2; x1 += k0 + 2u;
  TF_R(13) TF_R(15) TF_R(26) TF_R(6)
  x0 += k0; x1 += k1 + 3u;
  TF_R(17) TF_R(29) TF_R(16) TF_R(24)
  x0 += k1; x1 += ks2 + 4u;
  TF_R(13) TF_R(15) TF_R(26) TF_R(6)
  x0 += ks2; x1 += k0 + 5u;
#undef TF_R
  o0 = x0; o1 = x1;
}

// direct global->LDS DMA, 16B per lane at wave-uniform LDS base + lane*16
__device__ inline void gll16(const float* g, float* l) {
  __builtin_amdgcn_global_load_lds(
      (const __attribute__((address_space(1))) void*)g,
      (__attribute__((address_space(3))) void*)l, 16, 0, 0);
}

// 128x128x16-tile f32 GEMM, 256 threads, 8x8/thread (R10/R11 proven body).
// global_load_lds staging (zero staging VGPRs), double-buffered LDS,
// one barrier per K-step. No min-waves launch_bounds (R6: spill disaster).
// No A-swizzle: R12 proved the 4-way A bank conflict is non-binding.
__global__ __launch_bounds__(256)
void gemm_sk(const float* __restrict__ A0, int lda0,
             const float* __restrict__ W0, int koff0, int Klen0,
             const float* __restrict__ A1, int lda1,
             const float* __restrict__ W1, int koff1, int Klen1,
             int ldw,
             const float* __restrict__ bias,
             float* __restrict__ C0, float* __restrict__ C1, int ldc)
{
  const float* A; const float* W; float* C; int lda, koff, Klen;
  if (blockIdx.z == 0) { A = A0; lda = lda0; W = W0; koff = koff0; Klen = Klen0; C = C0; }
  else                 { A = A1; lda = lda1; W = W1; koff = koff1; Klen = Klen1; C = C1; }

  __shared__ float As[2][128 * 16];   // [row][k] row-major
  __shared__ float Ws[2][16 * 128];   // [k][n]   row-major
  const int tid = threadIdx.x;
  const int lane = tid & 63, wv = tid >> 6;
  const int m0 = blockIdx.y * 128;
  const int n0 = blockIdx.x * 128;
  const int tx = tid & 15, ty = tid >> 4;

  float acc[8][8];
  #pragma unroll
  for (int i = 0; i < 8; ++i)
    #pragma unroll
    for (int j = 0; j < 8; ++j) acc[i][j] = 0.0f;

  const int a_row_in = (lane >> 2);
  const int a_chunk  = (lane & 3) * 4;
  const int w_row_in = (lane >> 5);
  const int w_col    = (lane & 31) * 4;

  auto STAGE = [&](int buf, int kt) {
    const int k0 = koff + (kt << 4);
    #pragma unroll
    for (int i = 0; i < 2; ++i) {
      const int seg = wv * 2 + i;
      gll16(A + (size_t)(m0 + seg * 16 + a_row_in) * lda + (k0 + a_chunk),
            &As[buf][seg * 256]);
      gll16(W + (size_t)(k0 + seg * 2 + w_row_in) * ldw + (n0 + w_col),
            &Ws[buf][seg * 256]);
    }
  };

  const int nkt = Klen >> 4;
  STAGE(0, 0);
  asm volatile("s_waitcnt vmcnt(0)" ::: "memory");
  __syncthreads();

  int cur = 0;
  for (int kt = 0; kt < nkt; ++kt) {
    if (kt + 1 < nkt) STAGE(cur ^ 1, kt + 1);
    #pragma unroll
    for (int kk4 = 0; kk4 < 4; ++kk4) {
      float4 a4[8];
      #pragma unroll
      for (int mm = 0; mm < 8; ++mm)
        a4[mm] = *(const float4*)&As[cur][(ty * 8 + mm) * 16 + kk4 * 4];
      #pragma unroll
      for (int q = 0; q < 4; ++q) {
        const int kk = kk4 * 4 + q;
        float4 b0 = *(const float4*)&Ws[cur][kk * 128 + tx * 4];
        float4 b1 = *(const float4*)&Ws[cur][kk * 128 + tx * 4 + 64];
        float br[8] = {b0.x,b0.y,b0.z,b0.w,b1.x,b1.y,b1.z,b1.w};
        #pragma unroll
        for (int mm = 0; mm < 8; ++mm) {
          float av = (q == 0) ? a4[mm].x : (q == 1) ? a4[mm].y
                   : (q == 2) ? a4[mm].z : a4[mm].w;
          #pragma unroll
          for (int j = 0; j < 8; ++j)
            acc[mm][j] = fmaf(av, br[j], acc[mm][j]);
        }
      }
    }
    asm volatile("s_waitcnt vmcnt(0)" ::: "memory");
    __syncthreads();
    cur ^= 1;
  }

  const int wn = tx * 4;
  #pragma unroll
  for (int i = 0; i < 8; ++i) {
    const int m = m0 + ty * 8 + i;
    float* dst = C + (size_t)m * ldc + (n0 + wn);
    float4 o0, o1;
    o0.x = acc[i][0]; o0.y = acc[i][1]; o0.z = acc[i][2]; o0.w = acc[i][3];
    o1.x = acc[i][4]; o1.y = acc[i][5]; o1.z = acc[i][6]; o1.w = acc[i][7];
    if (bias) {
      o0.x += bias[n0+wn+0]; o0.y += bias[n0+wn+1];
      o0.z += bias[n0+wn+2]; o0.w += bias[n0+wn+3];
      o1.x += bias[n0+wn+64]; o1.y += bias[n0+wn+65];
      o1.z += bias[n0+wn+66]; o1.w += bias[n0+wn+67];
    }
    *(float4*)dst        = o0;
    *(float4*)(dst + 64) = o1;
  }
}

// LSTM gate update: z = z0 + z1 + bias
__global__ __launch_bounds__(256)
void gate_kernel(const float* __restrict__ z0, const float* __restrict__ z1,
                 const float* __restrict__ bias,
                 const float* __restrict__ cin,
                 float* __restrict__ hout, float* __restrict__ cout,
                 float* __restrict__ sh, float* __restrict__ sc)
{
  int idx = blockIdx.x * 256 + threadIdx.x;
  int b = idx >> 9, j = idx & 511;
  const size_t r2 = (size_t)b * 2048;
  float zi = z0[r2+j]      + z1[r2+j]      + bias[j];
  float zf = z0[r2+j+512]  + z1[r2+j+512]  + bias[j+512];
  float zg = z0[r2+j+1024] + z1[r2+j+1024] + bias[j+1024];
  float zo = z0[r2+j+1536] + z1[r2+j+1536] + bias[j+1536];
  float si = 1.0f/(1.0f+expf(-zi));
  float sf = 1.0f/(1.0f+expf(-zf));
  float so = 1.0f/(1.0f+expf(-zo));
  float c = sf * cin[idx] + si * tanhf(zg);
  float h = so * tanhf(c);
  cout[idx] = c; hout[idx] = h;
  if (sh) { sh[idx] = h; sc[idx] = c; }
}

// per-row max, log-sum-exp, entropy (H = log s - w/s, w = sum (x-m)e^{x-m})
__global__ __launch_bounds__(256)
void rowstat_kernel(const float* __restrict__ logits,
                    float* __restrict__ rowM, float* __restrict__ rowLS,
                    float* __restrict__ rowEnt)
{
  const int row = blockIdx.x;
  const float* x = logits + (size_t)row * VV;
  const int tid = threadIdx.x;
  float m = -INFINITY;
  for (int v = tid; v < VV; v += 256) m = fmaxf(m, x[v]);
  #pragma unroll
  for (int off = 32; off; off >>= 1) m = fmaxf(m, __shfl_down(m, off));
  __shared__ float sm[4], ssum[4], swsum[4];
  if ((tid & 63) == 0) sm[tid >> 6] = m;
  __syncthreads();
  m = fmaxf(fmaxf(sm[0], sm[1]), fmaxf(sm[2], sm[3]));
  float s = 0.0f, w = 0.0f;
  for (int v = tid; v < VV; v += 256) {
    float d = x[v] - m;
    float e = expf(d);
    s += e; w += d * e;
  }
  #pragma unroll
  for (int off = 32; off; off >>= 1) { s += __shfl_down(s, off); w += __shfl_down(w, off); }
  if ((tid & 63) == 0) { ssum[tid >> 6] = s; swsum[tid >> 6] = w; }
  __syncthreads();
  if (tid == 0) {
    s = ssum[0]+ssum[1]+ssum[2]+ssum[3];
    w = swsum[0]+swsum[1]+swsum[2]+swsum[3];
    float ls = logf(s);
    rowM[row] = m; rowLS[row] = ls; rowEnt[row] = ls - w / s;
  }
}

// Fused decode-pipeline kernel.
// Blocks [0, SB): sampler HALF-blocks — block s handles row l=s>>1, half
// h=s&1 over v in [0,16128) or [16128,32000) (both multiples of 256 so all
// lanes run uniform iteration counts; wave-shared-threshold shfl stays
// well-defined). Identical R7-proven filter math; partial (max,argmax) per
// (l,t,h) written to pv/pi, merged later by combine_kernel (low half wins
// ties -> global first-index tie-break preserved).
// Blocks [SB, SB+GB): gll GEMM computing the next chunk's logits.
__global__ __launch_bounds__(256)
void fused_sg(const float* __restrict__ logitsS,
              const float* __restrict__ rowM, const float* __restrict__ rowLS,
              const float* __restrict__ rowEnt,
              float* __restrict__ out, KeysArg keys, int bbaseS, int SB,
              const float* __restrict__ AG, const float* __restrict__ Wd,
              const float* __restrict__ bd, float* __restrict__ logitsG,
              float* __restrict__ pv, uint32_t* __restrict__ pi)
{
  __shared__ float As[2][128 * 16];
  __shared__ float Ws[2][16 * 128];
  __shared__ float rv[NT][4];
  __shared__ uint32_t ri[NT][4];

  const int tid = threadIdx.x;

  if ((int)blockIdx.x < SB) {
    // ---------------- sampler half-block path (R7 body) ----------------
    const int l = blockIdx.x >> 1;
    const int h = blockIdx.x & 1;
    const int b = bbaseS + l;
    const float* x = logitsS + (size_t)l * VV;
    const float m = rowM[l], ls = rowLS[l];
    const int vbeg = h ? VSPLIT : 0;
    const int vend = h ? VV : VSPLIT;

    float bv[NT];
    uint32_t bi[NT];
    float thr[NT];
    #pragma unroll
    for (int t = 0; t < NT; ++t) { bv[t] = -INFINITY; bi[t] = 0; thr[t] = 1.0f; }

    const uint32_t pbase = (uint32_t)b * (uint32_t)VV;
    for (int v = vbeg + tid; v < vend; v += 256) {
      const float lp = (x[v] - m) - ls;   // JAX order: (x - max) - logsum
      const uint32_t p = pbase + (uint32_t)v;
      #pragma unroll
      for (int t = 0; t < NT; ++t) {
        uint32_t o0, o1;
        tf2x32(keys.w[2*t], keys.w[2*t+1], 0u, p, o0, o1);
        const uint32_t bits = o0 ^ o1;
        const float uf = __uint_as_float((bits >> 9) | 0x3f800000u);
        if (__any(uf >= thr[t])) {
          float u = fmaxf(uf - 1.0f, 1.17549435e-38f);
          float g = -logf(-logf(u)) + lp;
          bool improved = (uf >= thr[t]) && (g > bv[t]);
          if (improved) { bv[t] = g; bi[t] = (uint32_t)v; }
          if (__any(improved)) {
            float wb = bv[t];
            #pragma unroll
            for (int off = 1; off < 64; off <<= 1)
              wb = fmaxf(wb, __shfl_xor(wb, off));
            float us = expf(-expf(-(wb + ls)));
            thr[t] = 1.0f + us * 0.999999f;   // conservative: never false-skip
          }
        }
      }
    }

    const int lane = tid & 63, wq = tid >> 6;
    #pragma unroll
    for (int t = 0; t < NT; ++t) {
      float v = bv[t]; uint32_t idx = bi[t];
      #pragma unroll
      for (int off = 32; off; off >>= 1) {
        float ov = __shfl_down(v, off);
        uint32_t oi = __shfl_down(idx, off);
        if (ov > v || (ov == v && oi < idx)) { v = ov; idx = oi; }
      }
      if (lane == 0) { rv[t][wq] = v; ri[t][wq] = idx; }
    }
    __syncthreads();
    if (tid < NT) {
      const int t = tid;
      float v = rv[t][0]; uint32_t idx = ri[t][0];
      #pragma unroll
      for (int q = 1; q < 4; ++q) {
        float ov = rv[t][q]; uint32_t oi = ri[t][q];
        if (ov > v || (ov == v && oi < idx)) { v = ov; idx = oi; }
      }
      pv[(size_t)(l * NT + t) * 2 + h] = v;
      pi[(size_t)(l * NT + t) * 2 + h] = idx;
    }
    return;
  }

  // ---------------- GEMM path (K=512, ldw=ldc=VV) ----------------
  const int gb = (int)blockIdx.x - SB;
  const int m0 = (gb / NXT) * 128;
  const int n0 = (gb % NXT) * 128;
  const int lane = tid & 63, wv = tid >> 6;
  const int tx = tid & 15, ty = tid >> 4;

  float acc[8][8];
  #pragma unroll
  for (int i = 0; i < 8; ++i)
    #pragma unroll
    for (int j = 0; j < 8; ++j) acc[i][j] = 0.0f;

  const int a_row_in = (lane >> 2);
  const int a_chunk  = (lane & 3) * 4;
  const int w_row_in = (lane >> 5);
  const int w_col    = (lane & 31) * 4;

  auto STAGE = [&](int buf, int kt) {
    const int k0 = kt << 4;
    #pragma unroll
    for (int i = 0; i < 2; ++i) {
      const int seg = wv * 2 + i;
      gll16(AG + (size_t)(m0 + seg * 16 + a_row_in) * 512 + (k0 + a_chunk),
            &As[buf][seg * 256]);
      gll16(Wd + (size_t)(k0 + seg * 2 + w_row_in) * VV + (n0 + w_col),
            &Ws[buf][seg * 256]);
    }
  };

  STAGE(0, 0);
  asm volatile("s_waitcnt vmcnt(0)" ::: "memory");
  __syncthreads();

  int cur = 0;
  for (int kt = 0; kt < 32; ++kt) {
    if (kt + 1 < 32) STAGE(cur ^ 1, kt + 1);
    #pragma unroll
    for (int kk4 = 0; kk4 < 4; ++kk4) {
      float4 a4[8];
      #pragma unroll
      for (int mm = 0; mm < 8; ++mm)
        a4[mm] = *(const float4*)&As[cur][(ty * 8 + mm) * 16 + kk4 * 4];
      #pragma unroll
      for (int q = 0; q < 4; ++q) {
        const int kk = kk4 * 4 + q;
        float4 b0 = *(const float4*)&Ws[cur][kk * 128 + tx * 4];
        float4 b1 = *(const float4*)&Ws[cur][kk * 128 + tx * 4 + 64];
        float br[8] = {b0.x,b0.y,b0.z,b0.w,b1.x,b1.y,b1.z,b1.w};
        #pragma unroll
        for (int mm = 0; mm < 8; ++mm) {
          float av = (q == 0) ? a4[mm].x : (q == 1) ? a4[mm].y
                   : (q == 2) ? a4[mm].z : a4[mm].w;
          #pragma unroll
          for (int j = 0; j < 8; ++j)
            acc[mm][j] = fmaf(av, br[j], acc[mm][j]);
        }
      }
    }
    asm volatile("s_waitcnt vmcnt(0)" ::: "memory");
    __syncthreads();
    cur ^= 1;
  }

  const int wn = tx * 4;
  #pragma unroll
  for (int i = 0; i < 8; ++i) {
    float* dst = logitsG + (size_t)(m0 + ty * 8 + i) * VV + (n0 + wn);
    float4 o0, o1;
    o0.x = acc[i][0] + bd[n0+wn+0];  o0.y = acc[i][1] + bd[n0+wn+1];
    o0.z = acc[i][2] + bd[n0+wn+2];  o0.w = acc[i][3] + bd[n0+wn+3];
    o1.x = acc[i][4] + bd[n0+wn+64]; o1.y = acc[i][5] + bd[n0+wn+65];
    o1.z = acc[i][6] + bd[n0+wn+66]; o1.w = acc[i][7] + bd[n0+wn+67];
    *(float4*)dst        = o0;
    *(float4*)(dst + 64) = o1;
  }
}

// Merge the two half-row partials and write outputs. v1 > v0 strict: low
// half (smaller indices) wins ties -> matches global first-index argmax.
__global__ __launch_bounds__(64)
void combine_kernel(const float* __restrict__ logits,
                    const float* __restrict__ rowM, const float* __restrict__ rowLS,
                    const float* __restrict__ rowEnt,
                    const float* __restrict__ pv, const uint32_t* __restrict__ pi,
                    float* __restrict__ out, int bbase)
{
  const int l = blockIdx.x;
  const int t = threadIdx.x;
  if (t >= NT) return;
  const size_t e = (size_t)(l * NT + t) * 2;
  float v0 = pv[e], v1 = pv[e + 1];
  uint32_t idx = (v1 > v0) ? pi[e + 1] : pi[e];
  const int b = bbase + l;
  const float* x = logits + (size_t)l * VV;
  const float m = rowM[l], ls = rowLS[l];
  out[(size_t)b * 30 + t]      = (float)idx;              // message
  out[(size_t)b * 30 + 15 + t] = 0.0f;                    // zero tail
  out[122880 + (size_t)t * BB + b] = (x[idx] - m) - ls;   // lp
  out[184320 + (size_t)t * BB + b] = rowEnt[l];           // ent
}

extern "C" void kernel_launch(void* const* d_in, const int* in_sizes, int n_in,
                              void* d_out, int out_size, void* d_ws, size_t ws_size,
                              hipStream_t stream)
{
  const float* inp = (const float*)d_in[0];
  const float* Wx0 = (const float*)d_in[1];
  const float* Wh0 = (const float*)d_in[2];
  const float* b0v = (const float*)d_in[3];
  const float* Wx1 = (const float*)d_in[4];
  const float* Wh1 = (const float*)d_in[5];
  const float* b1v = (const float*)d_in[6];
  const float* Wd  = (const float*)d_in[7];
  const float* bdv = (const float*)d_in[8];
  float* out = (float*)d_out;
  float* ws = (float*)d_ws;

  // ws layout (floats): h0,c0,h1,c1 | stats (2 chunk sets) | region.
  // LSTM phase: region = z0,z1. Decode: region = logits ping-pong | partials.
  float* h0 = ws;
  float* c0 = ws + (size_t)STF;
  float* h1 = ws + (size_t)2*STF;
  float* c1 = ws + (size_t)3*STF;
  float* rowM0  = ws + (size_t)4*STF;
  float* rowLS0 = rowM0 + 1024;
  float* rowEnt0 = rowLS0 + 1024;
  float* rowM1  = rowEnt0 + 1024;
  float* rowLS1 = rowM1 + 1024;
  float* rowEnt1 = rowLS1 + 1024;
  float* region = ws + (size_t)4*STF + 12288;
  float* z0 = region;
  float* z1 = region + (size_t)4096*2048;

  size_t ws_floats = ws_size / 4;
  size_t base = (size_t)4*STF + 12288;
  int CH = 512;   // decoder rows per chunk (ping-pong: need 2 buffers)
  while (CH > 128 && base + (size_t)2*CH*VV + (size_t)4*CH*NT > ws_floats) CH >>= 1;
  float* logitsA = region;
  float* logitsB = region + (size_t)CH*VV;
  float* pv = region + (size_t)2*CH*VV;                 // CH*NT*2 floats
  uint32_t* pi = (uint32_t*)(pv + (size_t)CH*NT*2);     // CH*NT*2 uints

  hipMemsetAsync(ws, 0, (size_t)4*STF*sizeof(float), stream);  // zero states

  for (int t = 0; t < 4; ++t) {
    gemm_sk<<<dim3(2048/128, 4096/128, 2), 256, 0, stream>>>(
        h0, 512, Wh0, 0, 512,
        inp + t*256, 1024, Wx0, 0, 256,
        2048, nullptr, z0, z1, 2048);
    gate_kernel<<<STF/256, 256, 0, stream>>>(
        z0, z1, b0v, c0, h0, c0,
        (t==3) ? out + 245760 : (float*)nullptr,
        (t==3) ? out + 245760 + STF : (float*)nullptr);
    gemm_sk<<<dim3(2048/128, 4096/128, 2), 256, 0, stream>>>(
        h0, 512, Wx1, 0, 512,
        h1, 512, Wh1, 0, 512,
        2048, nullptr, z0, z1, 2048);
    gate_kernel<<<STF/256, 256, 0, stream>>>(
        z0, z1, b1v, c1, h1, c1, (float*)nullptr, (float*)nullptr);
  }

  // host-side partitionable (fold-like) split of key(42):
  // key_t = (o0, o1) = threefry((0,42), x0=0, x1=t)
  KeysArg ka;
  for (int t = 0; t < NT; ++t) {
    uint32_t o0, o1;
    tf2x32(0u, 42u, 0u, (uint32_t)t, o0, o1);
    ka.w[2*t] = o0; ka.w[2*t+1] = o1;
  }

  const int nch = 4096 / CH;
  const int GB = NXT * (CH / 128);   // gemm blocks per chunk

  // pipeline: gemm(0); rowstat(0);
  // { F(sample-halves c || gemm c+1); combine(c); rowstat(c+1) }
  fused_sg<<<GB, 256, 0, stream>>>(
      nullptr, nullptr, nullptr, nullptr, out, ka, 0, 0,
      h1, Wd, bdv, logitsA, nullptr, nullptr);
  rowstat_kernel<<<CH, 256, 0, stream>>>(logitsA, rowM0, rowLS0, rowEnt0);

  for (int c = 0; c < nch; ++c) {
    float* lgS = (c & 1) ? logitsB : logitsA;
    float* lgG = (c & 1) ? logitsA : logitsB;
    float* rM = (c & 1) ? rowM1 : rowM0;
    float* rL = (c & 1) ? rowLS1 : rowLS0;
    float* rE = (c & 1) ? rowEnt1 : rowEnt0;
    const bool more = (c + 1 < nch);
    fused_sg<<<2*CH + (more ? GB : 0), 256, 0, stream>>>(
        lgS, rM, rL, rE, out, ka, c * CH, 2*CH,
        more ? (h1 + (size_t)(c + 1) * CH * 512) : h1, Wd, bdv, lgG, pv, pi);
    combine_kernel<<<CH, 64, 0, stream>>>(lgS, rM, rL, rE, pv, pi, out, c * CH);
    if (more) {
      float* rM2 = (c & 1) ? rowM0 : rowM1;
      float* rL2 = (c & 1) ? rowLS0 : rowLS1;
      float* rE2 = (c & 1) ? rowEnt0 : rowEnt1;
      rowstat_kernel<<<CH, 256, 0, stream>>>(lgG, rM2, rL2, rE2);
    }
  }
}

// Round 14
// 7201.868 us; speedup vs baseline: 1.0298x; 1.0152x over previous
//
#include <hip/hip_runtime.h>
#include <stdint.h>
#include <math.h>

#define BB 4096
#define HH 512
#define VV 32000
#define NT 15
#define STF 2097152   // BB*HH floats
#define NXT 250       // VV/128

struct KeysArg { uint32_t w[2*NT]; };

// JAX Threefry-2x32 (20 rounds, standard rotation/key schedule)
__host__ __device__ inline void tf2x32(uint32_t k0, uint32_t k1,
                                       uint32_t x0, uint32_t x1,
                                       uint32_t& o0, uint32_t& o1) {
  uint32_t ks2 = k0 ^ k1 ^ 0x1BD11BDAu;
  x0 += k0; x1 += k1;
#define TF_R(r) { x0 += x1; x1 = (x1 << (r)) | (x1 >> (32 - (r))); x1 ^= x0; }
  TF_R(13) TF_R(15) TF_R(26) TF_R(6)
  x0 += k1; x1 += ks2 + 1u;
  TF_R(17) TF_R(29) TF_R(16) TF_R(24)
  x0 += ks2; x1 += k0 + 2u;
  TF_R(13) TF_R(15) TF_R(26) TF_R(6)
  x0 += k0; x1 += k1 + 3u;
  TF_R(17) TF_R(29) TF_R(16) TF_R(24)
  x0 += k1; x1 += ks2 + 4u;
  TF_R(13) TF_R(15) TF_R(26) TF_R(6)
  x0 += ks2; x1 += k0 + 5u;
#undef TF_R
  o0 = x0; o1 = x1;
}

// direct global->LDS DMA, 16B per lane at wave-uniform LDS base + lane*16
__device__ inline void gll16(const float* g, float* l) {
  __builtin_amdgcn_global_load_lds(
      (const __attribute__((address_space(1))) void*)g,
      (__attribute__((address_space(3))) void*)l, 16, 0, 0);
}

// 128x128x16-tile f32 GEMM, 256 threads, 8x8/thread (R10 proven body).
// global_load_lds staging (zero staging VGPRs), double-buffered LDS,
// one barrier per K-step. No min-waves launch_bounds (R6: spill disaster).
__global__ __launch_bounds__(256)
void gemm_sk(const float* __restrict__ A0, int lda0,
             const float* __restrict__ W0, int koff0, int Klen0,
             const float* __restrict__ A1, int lda1,
             const float* __restrict__ W1, int koff1, int Klen1,
             int ldw,
             const float* __restrict__ bias,
             float* __restrict__ C0, float* __restrict__ C1, int ldc)
{
  const float* A; const float* W; float* C; int lda, koff, Klen;
  if (blockIdx.z == 0) { A = A0; lda = lda0; W = W0; koff = koff0; Klen = Klen0; C = C0; }
  else                 { A = A1; lda = lda1; W = W1; koff = koff1; Klen = Klen1; C = C1; }

  __shared__ float As[2][128 * 16];   // [row][k] row-major
  __shared__ float Ws[2][16 * 128];   // [k][n]   row-major
  const int tid = threadIdx.x;
  const int lane = tid & 63, wv = tid >> 6;
  const int m0 = blockIdx.y * 128;
  const int n0 = blockIdx.x * 128;
  const int tx = tid & 15, ty = tid >> 4;

  float acc[8][8];
  #pragma unroll
  for (int i = 0; i < 8; ++i)
    #pragma unroll
    for (int j = 0; j < 8; ++j) acc[i][j] = 0.0f;

  const int a_row_in = (lane >> 2);
  const int a_chunk  = (lane & 3) * 4;
  const int w_row_in = (lane >> 5);
  const int w_col    = (lane & 31) * 4;

  auto STAGE = [&](int buf, int kt) {
    const int k0 = koff + (kt << 4);
    #pragma unroll
    for (int i = 0; i < 2; ++i) {
      const int seg = wv * 2 + i;
      gll16(A + (size_t)(m0 + seg * 16 + a_row_in) * lda + (k0 + a_chunk),
            &As[buf][seg * 256]);
      gll16(W + (size_t)(k0 + seg * 2 + w_row_in) * ldw + (n0 + w_col),
            &Ws[buf][seg * 256]);
    }
  };

  const int nkt = Klen >> 4;
  STAGE(0, 0);
  asm volatile("s_waitcnt vmcnt(0)" ::: "memory");
  __syncthreads();

  int cur = 0;
  for (int kt = 0; kt < nkt; ++kt) {
    if (kt + 1 < nkt) STAGE(cur ^ 1, kt + 1);
    #pragma unroll
    for (int kk4 = 0; kk4 < 4; ++kk4) {
      float4 a4[8];
      #pragma unroll
      for (int mm = 0; mm < 8; ++mm)
        a4[mm] = *(const float4*)&As[cur][(ty * 8 + mm) * 16 + kk4 * 4];
      #pragma unroll
      for (int q = 0; q < 4; ++q) {
        const int kk = kk4 * 4 + q;
        float4 b0 = *(const float4*)&Ws[cur][kk * 128 + tx * 4];
        float4 b1 = *(const float4*)&Ws[cur][kk * 128 + tx * 4 + 64];
        float br[8] = {b0.x,b0.y,b0.z,b0.w,b1.x,b1.y,b1.z,b1.w};
        #pragma unroll
        for (int mm = 0; mm < 8; ++mm) {
          float av = (q == 0) ? a4[mm].x : (q == 1) ? a4[mm].y
                   : (q == 2) ? a4[mm].z : a4[mm].w;
          #pragma unroll
          for (int j = 0; j < 8; ++j)
            acc[mm][j] = fmaf(av, br[j], acc[mm][j]);
        }
      }
    }
    asm volatile("s_waitcnt vmcnt(0)" ::: "memory");
    __syncthreads();
    cur ^= 1;
  }

  const int wn = tx * 4;
  #pragma unroll
  for (int i = 0; i < 8; ++i) {
    const int m = m0 + ty * 8 + i;
    float* dst = C + (size_t)m * ldc + (n0 + wn);
    float4 o0, o1;
    o0.x = acc[i][0]; o0.y = acc[i][1]; o0.z = acc[i][2]; o0.w = acc[i][3];
    o1.x = acc[i][4]; o1.y = acc[i][5]; o1.z = acc[i][6]; o1.w = acc[i][7];
    if (bias) {
      o0.x += bias[n0+wn+0]; o0.y += bias[n0+wn+1];
      o0.z += bias[n0+wn+2]; o0.w += bias[n0+wn+3];
      o1.x += bias[n0+wn+64]; o1.y += bias[n0+wn+65];
      o1.z += bias[n0+wn+66]; o1.w += bias[n0+wn+67];
    }
    *(float4*)dst        = o0;
    *(float4*)(dst + 64) = o1;
  }
}

// LSTM gate update: z = z0 + z1 + bias
__global__ __launch_bounds__(256)
void gate_kernel(const float* __restrict__ z0, const float* __restrict__ z1,
                 const float* __restrict__ bias,
                 const float* __restrict__ cin,
                 float* __restrict__ hout, float* __restrict__ cout,
                 float* __restrict__ sh, float* __restrict__ sc)
{
  int idx = blockIdx.x * 256 + threadIdx.x;
  int b = idx >> 9, j = idx & 511;
  const size_t r2 = (size_t)b * 2048;
  float zi = z0[r2+j]      + z1[r2+j]      + bias[j];
  float zf = z0[r2+j+512]  + z1[r2+j+512]  + bias[j+512];
  float zg = z0[r2+j+1024] + z1[r2+j+1024] + bias[j+1024];
  float zo = z0[r2+j+1536] + z1[r2+j+1536] + bias[j+1536];
  float si = 1.0f/(1.0f+expf(-zi));
  float sf = 1.0f/(1.0f+expf(-zf));
  float so = 1.0f/(1.0f+expf(-zo));
  float c = sf * cin[idx] + si * tanhf(zg);
  float h = so * tanhf(c);
  cout[idx] = c; hout[idx] = h;
  if (sh) { sh[idx] = h; sc[idx] = c; }
}

// per-row max, log-sum-exp, entropy (H = log s - w/s, w = sum (x-m)e^{x-m})
__global__ __launch_bounds__(256)
void rowstat_kernel(const float* __restrict__ logits,
                    float* __restrict__ rowM, float* __restrict__ rowLS,
                    float* __restrict__ rowEnt)
{
  const int row = blockIdx.x;
  const float* x = logits + (size_t)row * VV;
  const int tid = threadIdx.x;
  float m = -INFINITY;
  for (int v = tid; v < VV; v += 256) m = fmaxf(m, x[v]);
  #pragma unroll
  for (int off = 32; off; off >>= 1) m = fmaxf(m, __shfl_down(m, off));
  __shared__ float sm[4], ssum[4], swsum[4];
  if ((tid & 63) == 0) sm[tid >> 6] = m;
  __syncthreads();
  m = fmaxf(fmaxf(sm[0], sm[1]), fmaxf(sm[2], sm[3]));
  float s = 0.0f, w = 0.0f;
  for (int v = tid; v < VV; v += 256) {
    float d = x[v] - m;
    float e = expf(d);
    s += e; w += d * e;
  }
  #pragma unroll
  for (int off = 32; off; off >>= 1) { s += __shfl_down(s, off); w += __shfl_down(w, off); }
  if ((tid & 63) == 0) { ssum[tid >> 6] = s; swsum[tid >> 6] = w; }
  __syncthreads();
  if (tid == 0) {
    s = ssum[0]+ssum[1]+ssum[2]+ssum[3];
    w = swsum[0]+swsum[1]+swsum[2]+swsum[3];
    float ls = logf(s);
    rowM[row] = m; rowLS[row] = ls; rowEnt[row] = ls - w / s;
  }
}

// Fused decode-pipeline kernel (R11 proven config): blocks [0,SB) run the
// R7-proven sampler for chunk c; blocks [SB, SB+GB) run the gll GEMM for
// chunk c+1. NEW (R14): GEMM block index remapped so the MT m-tile blocks
// sharing one Wd panel are 8 dispatch-slots apart (same XCD under bid%8
// round-robin) and temporally adjacent -> panel fetched once per XCD L2,
// 3/4 reads become L2 hits instead of 900-cyc HBM misses.
__global__ __launch_bounds__(256)
void fused_sg(const float* __restrict__ logitsS,
              const float* __restrict__ rowM, const float* __restrict__ rowLS,
              const float* __restrict__ rowEnt,
              float* __restrict__ out, KeysArg keys, int bbaseS, int SB,
              const float* __restrict__ AG, const float* __restrict__ Wd,
              const float* __restrict__ bd, float* __restrict__ logitsG,
              int MT)
{
  __shared__ float As[2][128 * 16];
  __shared__ float Ws[2][16 * 128];
  __shared__ float rv[NT][4];
  __shared__ uint32_t ri[NT][4];

  const int tid = threadIdx.x;

  if ((int)blockIdx.x < SB) {
    // ---------------- sampler path (R7 body) ----------------
    const int l = blockIdx.x;
    const int b = bbaseS + l;
    const float* x = logitsS + (size_t)l * VV;
    const float m = rowM[l], ls = rowLS[l];

    float bv[NT];
    uint32_t bi[NT];
    float thr[NT];
    #pragma unroll
    for (int t = 0; t < NT; ++t) { bv[t] = -INFINITY; bi[t] = 0; thr[t] = 1.0f; }

    const uint32_t pbase = (uint32_t)b * (uint32_t)VV;
    for (int v = tid; v < VV; v += 256) {
      const float lp = (x[v] - m) - ls;   // JAX order: (x - max) - logsum
      const uint32_t p = pbase + (uint32_t)v;
      #pragma unroll
      for (int t = 0; t < NT; ++t) {
        uint32_t o0, o1;
        tf2x32(keys.w[2*t], keys.w[2*t+1], 0u, p, o0, o1);
        const uint32_t bits = o0 ^ o1;
        const float uf = __uint_as_float((bits >> 9) | 0x3f800000u);
        if (__any(uf >= thr[t])) {
          float u = fmaxf(uf - 1.0f, 1.17549435e-38f);
          float g = -logf(-logf(u)) + lp;
          bool improved = (uf >= thr[t]) && (g > bv[t]);
          if (improved) { bv[t] = g; bi[t] = (uint32_t)v; }
          if (__any(improved)) {
            float wb = bv[t];
            #pragma unroll
            for (int off = 1; off < 64; off <<= 1)
              wb = fmaxf(wb, __shfl_xor(wb, off));
            float us = expf(-expf(-(wb + ls)));
            thr[t] = 1.0f + us * 0.999999f;   // conservative: never false-skip
          }
        }
      }
    }

    const int lane = tid & 63, wq = tid >> 6;
    #pragma unroll
    for (int t = 0; t < NT; ++t) {
      float v = bv[t]; uint32_t idx = bi[t];
      #pragma unroll
      for (int off = 32; off; off >>= 1) {
        float ov = __shfl_down(v, off);
        uint32_t oi = __shfl_down(idx, off);
        if (ov > v || (ov == v && oi < idx)) { v = ov; idx = oi; }
      }
      if (lane == 0) { rv[t][wq] = v; ri[t][wq] = idx; }
    }
    __syncthreads();
    if (tid < NT) {
      const int t = tid;
      float v = rv[t][0]; uint32_t idx = ri[t][0];
      #pragma unroll
      for (int q = 1; q < 4; ++q) {
        float ov = rv[t][q]; uint32_t oi = ri[t][q];
        if (ov > v || (ov == v && oi < idx)) { v = ov; idx = oi; }
      }
      out[(size_t)b * 30 + t]      = (float)idx;              // message
      out[(size_t)b * 30 + 15 + t] = 0.0f;                    // zero tail
      out[122880 + (size_t)t * BB + b] = (x[idx] - m) - ls;   // lp
      out[184320 + (size_t)t * BB + b] = rowEnt[l];           // ent
    }
    return;
  }

  // ---------------- GEMM path (K=512, ldw=ldc=VV) ----------------
  // XCD-aware remap: group of 8*MT blocks covers 8 n-tiles x MT m-tiles,
  // n fastest within group -> W-panel sharers are 8 apart (same XCD).
  const int gb = (int)blockIdx.x - SB;
  const int GRP = 8 * MT;
  const int nfullgrp = NXT / 8;          // 31 full groups of 8 n-tiles
  int mIdx, nIdx;
  if (gb < nfullgrp * GRP) {
    const int grp = gb / GRP, w = gb % GRP;
    nIdx = grp * 8 + (w & 7);
    mIdx = w >> 3;
  } else {
    const int r = gb - nfullgrp * GRP;
    const int ntail = NXT - nfullgrp * 8;  // 2
    nIdx = nfullgrp * 8 + (r % ntail);
    mIdx = r / ntail;
  }
  const int m0 = mIdx * 128;
  const int n0 = nIdx * 128;
  const int lane = tid & 63, wv = tid >> 6;
  const int tx = tid & 15, ty = tid >> 4;

  float acc[8][8];
  #pragma unroll
  for (int i = 0; i < 8; ++i)
    #pragma unroll
    for (int j = 0; j < 8; ++j) acc[i][j] = 0.0f;

  const int a_row_in = (lane >> 2);
  const int a_chunk  = (lane & 3) * 4;
  const int w_row_in = (lane >> 5);
  const int w_col    = (lane & 31) * 4;

  auto STAGE = [&](int buf, int kt) {
    const int k0 = kt << 4;
    #pragma unroll
    for (int i = 0; i < 2; ++i) {
      const int seg = wv * 2 + i;
      gll16(AG + (size_t)(m0 + seg * 16 + a_row_in) * 512 + (k0 + a_chunk),
            &As[buf][seg * 256]);
      gll16(Wd + (size_t)(k0 + seg * 2 + w_row_in) * VV + (n0 + w_col),
            &Ws[buf][seg * 256]);
    }
  };

  STAGE(0, 0);
  asm volatile("s_waitcnt vmcnt(0)" ::: "memory");
  __syncthreads();

  int cur = 0;
  for (int kt = 0; kt < 32; ++kt) {
    if (kt + 1 < 32) STAGE(cur ^ 1, kt + 1);
    #pragma unroll
    for (int kk4 = 0; kk4 < 4; ++kk4) {
      float4 a4[8];
      #pragma unroll
      for (int mm = 0; mm < 8; ++mm)
        a4[mm] = *(const float4*)&As[cur][(ty * 8 + mm) * 16 + kk4 * 4];
      #pragma unroll
      for (int q = 0; q < 4; ++q) {
        const int kk = kk4 * 4 + q;
        float4 b0 = *(const float4*)&Ws[cur][kk * 128 + tx * 4];
        float4 b1 = *(const float4*)&Ws[cur][kk * 128 + tx * 4 + 64];
        float br[8] = {b0.x,b0.y,b0.z,b0.w,b1.x,b1.y,b1.z,b1.w};
        #pragma unroll
        for (int mm = 0; mm < 8; ++mm) {
          float av = (q == 0) ? a4[mm].x : (q == 1) ? a4[mm].y
                   : (q == 2) ? a4[mm].z : a4[mm].w;
          #pragma unroll
          for (int j = 0; j < 8; ++j)
            acc[mm][j] = fmaf(av, br[j], acc[mm][j]);
        }
      }
    }
    asm volatile("s_waitcnt vmcnt(0)" ::: "memory");
    __syncthreads();
    cur ^= 1;
  }

  const int wn = tx * 4;
  #pragma unroll
  for (int i = 0; i < 8; ++i) {
    float* dst = logitsG + (size_t)(m0 + ty * 8 + i) * VV + (n0 + wn);
    float4 o0, o1;
    o0.x = acc[i][0] + bd[n0+wn+0];  o0.y = acc[i][1] + bd[n0+wn+1];
    o0.z = acc[i][2] + bd[n0+wn+2];  o0.w = acc[i][3] + bd[n0+wn+3];
    o1.x = acc[i][4] + bd[n0+wn+64]; o1.y = acc[i][5] + bd[n0+wn+65];
    o1.z = acc[i][6] + bd[n0+wn+66]; o1.w = acc[i][7] + bd[n0+wn+67];
    *(float4*)dst        = o0;
    *(float4*)(dst + 64) = o1;
  }
}

extern "C" void kernel_launch(void* const* d_in, const int* in_sizes, int n_in,
                              void* d_out, int out_size, void* d_ws, size_t ws_size,
                              hipStream_t stream)
{
  const float* inp = (const float*)d_in[0];
  const float* Wx0 = (const float*)d_in[1];
  const float* Wh0 = (const float*)d_in[2];
  const float* b0v = (const float*)d_in[3];
  const float* Wx1 = (const float*)d_in[4];
  const float* Wh1 = (const float*)d_in[5];
  const float* b1v = (const float*)d_in[6];
  const float* Wd  = (const float*)d_in[7];
  const float* bdv = (const float*)d_in[8];
  float* out = (float*)d_out;
  float* ws = (float*)d_ws;

  // ws layout (floats): h0,c0,h1,c1 | stats (2 chunk sets) | region.
  // LSTM phase: region = z0,z1. Decode: region = logits ping-pong.
  float* h0 = ws;
  float* c0 = ws + (size_t)STF;
  float* h1 = ws + (size_t)2*STF;
  float* c1 = ws + (size_t)3*STF;
  float* rowM0  = ws + (size_t)4*STF;
  float* rowLS0 = rowM0 + 1024;
  float* rowEnt0 = rowLS0 + 1024;
  float* rowM1  = rowEnt0 + 1024;
  float* rowLS1 = rowM1 + 1024;
  float* rowEnt1 = rowLS1 + 1024;
  float* region = ws + (size_t)4*STF + 12288;
  float* z0 = region;
  float* z1 = region + (size_t)4096*2048;

  size_t ws_floats = ws_size / 4;
  size_t base = (size_t)4*STF + 12288;
  int CH = 512;   // decoder rows per chunk (ping-pong: need 2 buffers)
  while (CH > 128 && base + (size_t)2*CH*VV > ws_floats) CH >>= 1;
  float* logitsA = region;
  float* logitsB = region + (size_t)CH*VV;

  hipMemsetAsync(ws, 0, (size_t)4*STF*sizeof(float), stream);  // zero states

  for (int t = 0; t < 4; ++t) {
    gemm_sk<<<dim3(2048/128, 4096/128, 2), 256, 0, stream>>>(
        h0, 512, Wh0, 0, 512,
        inp + t*256, 1024, Wx0, 0, 256,
        2048, nullptr, z0, z1, 2048);
    gate_kernel<<<STF/256, 256, 0, stream>>>(
        z0, z1, b0v, c0, h0, c0,
        (t==3) ? out + 245760 : (float*)nullptr,
        (t==3) ? out + 245760 + STF : (float*)nullptr);
    gemm_sk<<<dim3(2048/128, 4096/128, 2), 256, 0, stream>>>(
        h0, 512, Wx1, 0, 512,
        h1, 512, Wh1, 0, 512,
        2048, nullptr, z0, z1, 2048);
    gate_kernel<<<STF/256, 256, 0, stream>>>(
        z0, z1, b1v, c1, h1, c1, (float*)nullptr, (float*)nullptr);
  }

  // host-side partitionable (fold-like) split of key(42):
  // key_t = (o0, o1) = threefry((0,42), x0=0, x1=t)
  KeysArg ka;
  for (int t = 0; t < NT; ++t) {
    uint32_t o0, o1;
    tf2x32(0u, 42u, 0u, (uint32_t)t, o0, o1);
    ka.w[2*t] = o0; ka.w[2*t+1] = o1;
  }

  const int nch = 4096 / CH;
  const int MT = CH / 128;
  const int GB = NXT * MT;   // gemm blocks per chunk

  // pipeline: gemm(0); rowstat(0); { F(sample c || gemm c+1); rowstat(c+1) }
  fused_sg<<<GB, 256, 0, stream>>>(
      nullptr, nullptr, nullptr, nullptr, out, ka, 0, 0,
      h1, Wd, bdv, logitsA, MT);
  rowstat_kernel<<<CH, 256, 0, stream>>>(logitsA, rowM0, rowLS0, rowEnt0);

  for (int c = 0; c < nch; ++c) {
    float* lgS = (c & 1) ? logitsB : logitsA;
    float* lgG = (c & 1) ? logitsA : logitsB;
    float* rM = (c & 1) ? rowM1 : rowM0;
    float* rL = (c & 1) ? rowLS1 : rowLS0;
    float* rE = (c & 1) ? rowEnt1 : rowEnt0;
    const bool more = (c + 1 < nch);
    fused_sg<<<CH + (more ? GB : 0), 256, 0, stream>>>(
        lgS, rM, rL, rE, out, ka, c * CH, CH,
        more ? (h1 + (size_t)(c + 1) * CH * 512) : h1, Wd, bdv, lgG, MT);
    if (more) {
      float* rM2 = (c & 1) ? rowM0 : rowM1;
      float* rL2 = (c & 1) ? rowLS0 : rowLS1;
      float* rE2 = (c & 1) ? rowEnt0 : rowEnt1;
      rowstat_kernel<<<CH, 256, 0, stream>>>(lgG, rM2, rL2, rE2);
    }
  }
}